// Round 3
// baseline (687.778 us; speedup 1.0000x reference)
//
#include <hip/hip_runtime.h>

#define NN 100000
#define EE 1000000
#define FF 128
#define HH 64
#define GG 128
#define NB 391   // scan blocks: 391*256 = 100096 >= NN

// ---------- CSR build ----------
__global__ void k_hist(const int* __restrict__ ei, int* __restrict__ cnt) {
    int e = blockIdx.x * 256 + threadIdx.x;
    if (e < EE) atomicAdd(&cnt[ei[EE + e]], 1);
}

__global__ void k_scan1(const int* __restrict__ cnt, int* __restrict__ part) {
    int i = blockIdx.x * 256 + threadIdx.x;
    int v = (i < NN) ? cnt[i] : 0;
    for (int o = 1; o < 64; o <<= 1) v += __shfl_xor(v, o);
    __shared__ int ws[4];
    if ((threadIdx.x & 63) == 0) ws[threadIdx.x >> 6] = v;
    __syncthreads();
    if (threadIdx.x == 0) part[blockIdx.x] = ws[0] + ws[1] + ws[2] + ws[3];
}

__global__ void k_scan2(int* __restrict__ part) {   // exclusive scan, 1 block
    __shared__ int buf[512];
    int t = threadIdx.x;
    int v = (t < NB) ? part[t] : 0;
    buf[t] = v; __syncthreads();
    for (int o = 1; o < 512; o <<= 1) {
        int u = (t >= o) ? buf[t - o] : 0;
        __syncthreads();
        buf[t] += u;
        __syncthreads();
    }
    if (t < NB) part[t] = buf[t] - v;
}

__global__ void k_scan3(const int* __restrict__ cnt, const int* __restrict__ part,
                        int* __restrict__ row_ptr, int* __restrict__ cursor,
                        float* __restrict__ dis) {
    int i = blockIdx.x * 256 + threadIdx.x;
    int v = (i < NN) ? cnt[i] : 0;
    int lane = threadIdx.x & 63, w = threadIdx.x >> 6;
    int incl = v;
    for (int o = 1; o < 64; o <<= 1) { int u = __shfl_up(incl, o); if (lane >= o) incl += u; }
    __shared__ int ws[4];
    if (lane == 63) ws[w] = incl;
    __syncthreads();
    int woff = 0;
    for (int k = 0; k < w; ++k) woff += ws[k];
    int excl = incl - v + woff + part[blockIdx.x];
    if (i < NN) {
        row_ptr[i] = excl;
        cursor[i]  = excl;
        dis[i] = rsqrtf((float)(v + 1));
    }
    if (i == 0) row_ptr[NN] = EE;
}

__global__ void k_place(const int* __restrict__ ei, int* __restrict__ cursor,
                        int* __restrict__ srcs) {
    int e = blockIdx.x * 256 + threadIdx.x;
    if (e < EE) {
        int d = ei[EE + e];
        int p = atomicAdd(&cursor[d], 1);
        srcs[p] = ei[e];
    }
}

// ---------- dense: Y[N,64] = (X[N,K] @ W[K,64]) * dis[row] ----------
template<int K>
__global__ void k_matmul_s(const float* __restrict__ X, const float* __restrict__ W,
                           const float* __restrict__ dis, float* __restrict__ Y) {
    __shared__ float Wl[K * HH];
    for (int i = threadIdx.x; i < K * HH; i += 256) Wl[i] = W[i];
    __syncthreads();
    const int col  = threadIdx.x & 63;
    const int rsub = threadIdx.x >> 6;
    const int rowBase = blockIdx.x * 32;
    for (int rr = rsub; rr < 32; rr += 4) {
        const int r = rowBase + rr;
        if (r >= NN) continue;
        const float4* xr = (const float4*)(X + (size_t)r * K);
        float acc = 0.0f;
#pragma unroll
        for (int k4 = 0; k4 < K / 4; ++k4) {
            float4 xv = xr[k4];
            acc = fmaf(xv.x, Wl[(k4 * 4 + 0) * HH + col], acc);
            acc = fmaf(xv.y, Wl[(k4 * 4 + 1) * HH + col], acc);
            acc = fmaf(xv.z, Wl[(k4 * 4 + 2) * HH + col], acc);
            acc = fmaf(xv.w, Wl[(k4 * 4 + 3) * HH + col], acc);
        }
        Y[(size_t)r * HH + col] = acc * dis[r];
    }
}

// ---------- gather conv: out[d] = relu(dd*(sum Hs[src] + Hs[d]) + b) ----------
// One wave per node; 4 lane-groups x 16 lanes: 4 edges in flight, float4/lane.
// Unroll-by-2 -> 8 independent gather chains per wave.
template<bool POOL>
__global__ __launch_bounds__(256) void
k_gconv(const int* __restrict__ row_ptr, const int* __restrict__ srcs,
        const float* __restrict__ dis, const float* __restrict__ Hs,
        const float* __restrict__ b, float* __restrict__ Out,
        const int* __restrict__ batch, float* __restrict__ g) {
    const int node = blockIdx.x * 4 + (threadIdx.x >> 6);
    const int lane = threadIdx.x & 63;
    const int grp  = lane >> 4;          // 0..3: edge slot
    const int sub  = lane & 15;          // 0..15: col/4
    const int p1 = row_ptr[node + 1];
    int p = row_ptr[node] + grp;
    float4 a0 = {0.f, 0.f, 0.f, 0.f}, a1 = {0.f, 0.f, 0.f, 0.f};
    for (; p + 4 < p1; p += 8) {
        const int s0 = srcs[p];
        const int s1 = srcs[p + 4];
        const float4 v0 = *(const float4*)(Hs + (size_t)s0 * HH + sub * 4);
        const float4 v1 = *(const float4*)(Hs + (size_t)s1 * HH + sub * 4);
        a0.x += v0.x; a0.y += v0.y; a0.z += v0.z; a0.w += v0.w;
        a1.x += v1.x; a1.y += v1.y; a1.z += v1.z; a1.w += v1.w;
    }
    if (p < p1) {
        const int s = srcs[p];
        const float4 v = *(const float4*)(Hs + (size_t)s * HH + sub * 4);
        a0.x += v.x; a0.y += v.y; a0.z += v.z; a0.w += v.w;
    }
    a0.x += a1.x; a0.y += a1.y; a0.z += a1.z; a0.w += a1.w;
#pragma unroll
    for (int o = 16; o < 64; o <<= 1) {
        a0.x += __shfl_xor(a0.x, o);
        a0.y += __shfl_xor(a0.y, o);
        a0.z += __shfl_xor(a0.z, o);
        a0.w += __shfl_xor(a0.w, o);
    }
    const float dd = dis[node];
    const float4 hv = *(const float4*)(Hs + (size_t)node * HH + sub * 4);
    const float4 bv = *(const float4*)(b + sub * 4);
    float4 v;
    v.x = fmaxf((a0.x + hv.x) * dd + bv.x, 0.0f);
    v.y = fmaxf((a0.y + hv.y) * dd + bv.y, 0.0f);
    v.z = fmaxf((a0.z + hv.z) * dd + bv.z, 0.0f);
    v.w = fmaxf((a0.w + hv.w) * dd + bv.w, 0.0f);
    if (grp == 0) {
        if (POOL) {
            float* gp = g + (size_t)batch[node] * HH + sub * 4;
            unsafeAtomicAdd(gp + 0, v.x);
            unsafeAtomicAdd(gp + 1, v.y);
            unsafeAtomicAdd(gp + 2, v.z);
            unsafeAtomicAdd(gp + 3, v.w);
        } else {
            *(float4*)(Out + (size_t)node * HH + sub * 4) = v;
        }
    }
}

// ---------- head ----------
__global__ void k_head1(const float* __restrict__ g, const float* __restrict__ W,
                        const float* __restrict__ b, float* __restrict__ g2) {
    const int idx = blockIdx.x * 256 + threadIdx.x;
    const int row = idx >> 6;
    const int col = idx & 63;
    const float* gr = g + (size_t)row * HH;
    float acc = b[col];
#pragma unroll
    for (int k = 0; k < HH; ++k) acc = fmaf(gr[k], W[k * HH + col], acc);
    g2[idx] = acc > 0.0f ? acc : 0.0f;
}

__global__ void k_head2(const float* __restrict__ g2, const float* __restrict__ W,
                        const float* __restrict__ b, float* __restrict__ out) {
    const int r = threadIdx.x;
    if (r >= GG) return;
    const float* gr = g2 + (size_t)r * HH;
    float acc = 0.0f;
#pragma unroll
    for (int k = 0; k < HH; ++k) acc = fmaf(gr[k], W[k], acc);
    out[r] = acc + b[0];
}

extern "C" void kernel_launch(void* const* d_in, const int* in_sizes, int n_in,
                              void* d_out, int out_size, void* d_ws, size_t ws_size,
                              hipStream_t stream) {
    const float* x   = (const float*)d_in[0];
    const int*   ei  = (const int*)d_in[1];
    const int*   bat = (const int*)d_in[2];
    const float* W1  = (const float*)d_in[3];
    const float* b1  = (const float*)d_in[4];
    const float* W2  = (const float*)d_in[5];
    const float* b2  = (const float*)d_in[6];
    const float* Wl1 = (const float*)d_in[7];
    const float* bl1 = (const float*)d_in[8];
    const float* Wl2 = (const float*)d_in[9];
    const float* bl2 = (const float*)d_in[10];
    float* out = (float*)d_out;

    char* w = (char*)d_ws;
    float* dis     = (float*)(w);                    // 400128 B
    int*   cnt     = (int*)  (w + 400128);           // 400128 B
    int*   row_ptr = (int*)  (w + 800256);           // 400384 B (N+1)
    int*   cursor  = (int*)  (w + 1200640);          // 400128 B
    int*   part    = (int*)  (w + 1600768);          // 2048 B
    int*   srcs    = (int*)  (w + 1602816);          // 4000000 B
    float* B       = (float*)(w + 5602816);          // 25.6 MB
    float* A       = (float*)(w + 31202816);         // 25.6 MB
    float* g       = (float*)(w + 56802816);         // 32 KB
    float* g2      = g + GG * HH;

    // ---- CSR build (once; reused by both convs) ----
    hipMemsetAsync(cnt, 0, (size_t)NN * sizeof(int), stream);
    k_hist <<<(EE + 255) / 256, 256, 0, stream>>>(ei, cnt);
    k_scan1<<<NB, 256, 0, stream>>>(cnt, part);
    k_scan2<<<1, 512, 0, stream>>>(part);
    k_scan3<<<NB, 256, 0, stream>>>(cnt, part, row_ptr, cursor, dis);
    k_place<<<(EE + 255) / 256, 256, 0, stream>>>(ei, cursor, srcs);

    // ---- conv1 ----
    k_matmul_s<FF><<<(NN + 31) / 32, 256, 0, stream>>>(x, W1, dis, B);
    k_gconv<false><<<NN / 4, 256, 0, stream>>>(row_ptr, srcs, dis, B, b1, A, nullptr, nullptr);

    // ---- conv2 (pool fused) ----
    k_matmul_s<HH><<<(NN + 31) / 32, 256, 0, stream>>>(A, W2, dis, B);
    hipMemsetAsync(g, 0, (size_t)GG * HH * sizeof(float), stream);
    k_gconv<true><<<NN / 4, 256, 0, stream>>>(row_ptr, srcs, dis, B, b2, nullptr, bat, g);

    // ---- head ----
    k_head1<<<(GG * HH) / 256, 256, 0, stream>>>(g, Wl1, bl1, g2);
    k_head2<<<1, 128, 0, stream>>>(g2, Wl2, bl2, out);
}

// Round 4
// 446.040 us; speedup vs baseline: 1.5420x; 1.5420x over previous
//
#include <hip/hip_runtime.h>

#define NN 100000
#define EE 1000000
#define FF 128
#define HH 64
#define GG 128
#define NB 391   // scan blocks: 391*256 = 100096 >= NN

// ---------- CSR build ----------
__global__ void k_hist(const int* __restrict__ ei, int* __restrict__ cnt) {
    int e = blockIdx.x * 256 + threadIdx.x;
    if (e < EE) atomicAdd(&cnt[ei[EE + e]], 1);
}

__global__ void k_scan1(const int* __restrict__ cnt, int* __restrict__ part) {
    int i = blockIdx.x * 256 + threadIdx.x;
    int v = (i < NN) ? cnt[i] : 0;
    for (int o = 1; o < 64; o <<= 1) v += __shfl_xor(v, o);
    __shared__ int ws[4];
    if ((threadIdx.x & 63) == 0) ws[threadIdx.x >> 6] = v;
    __syncthreads();
    if (threadIdx.x == 0) part[blockIdx.x] = ws[0] + ws[1] + ws[2] + ws[3];
}

__global__ void k_scan2(int* __restrict__ part) {   // exclusive scan, 1 block
    __shared__ int buf[512];
    int t = threadIdx.x;
    int v = (t < NB) ? part[t] : 0;
    buf[t] = v; __syncthreads();
    for (int o = 1; o < 512; o <<= 1) {
        int u = (t >= o) ? buf[t - o] : 0;
        __syncthreads();
        buf[t] += u;
        __syncthreads();
    }
    if (t < NB) part[t] = buf[t] - v;
}

__global__ void k_scan3(const int* __restrict__ cnt, const int* __restrict__ part,
                        int* __restrict__ row_ptr, int* __restrict__ cursor,
                        float* __restrict__ dis) {
    int i = blockIdx.x * 256 + threadIdx.x;
    int v = (i < NN) ? cnt[i] : 0;
    int lane = threadIdx.x & 63, w = threadIdx.x >> 6;
    int incl = v;
    for (int o = 1; o < 64; o <<= 1) { int u = __shfl_up(incl, o); if (lane >= o) incl += u; }
    __shared__ int ws[4];
    if (lane == 63) ws[w] = incl;
    __syncthreads();
    int woff = 0;
    for (int k = 0; k < w; ++k) woff += ws[k];
    int excl = incl - v + woff + part[blockIdx.x];
    if (i < NN) {
        row_ptr[i] = excl;
        cursor[i]  = excl;
        dis[i] = rsqrtf((float)(v + 1));
    }
    if (i == 0) row_ptr[NN] = EE;
}

__global__ void k_place(const int* __restrict__ ei, int* __restrict__ cursor,
                        int* __restrict__ srcs) {
    int e = blockIdx.x * 256 + threadIdx.x;
    if (e < EE) {
        int d = ei[EE + e];
        int p = atomicAdd(&cursor[d], 1);
        srcs[p] = ei[e];
    }
}

// ---------- dense: Y[N,64] = (X[N,K] @ W[K,64]) * dis[row] ----------
template<int K>
__global__ void k_matmul_s(const float* __restrict__ X, const float* __restrict__ W,
                           const float* __restrict__ dis, float* __restrict__ Y) {
    __shared__ float Wl[K * HH];
    for (int i = threadIdx.x; i < K * HH; i += 256) Wl[i] = W[i];
    __syncthreads();
    const int col  = threadIdx.x & 63;
    const int rsub = threadIdx.x >> 6;
    const int rowBase = blockIdx.x * 32;
    for (int rr = rsub; rr < 32; rr += 4) {
        const int r = rowBase + rr;
        if (r >= NN) continue;
        const float4* xr = (const float4*)(X + (size_t)r * K);
        float acc = 0.0f;
#pragma unroll
        for (int k4 = 0; k4 < K / 4; ++k4) {
            float4 xv = xr[k4];
            acc = fmaf(xv.x, Wl[(k4 * 4 + 0) * HH + col], acc);
            acc = fmaf(xv.y, Wl[(k4 * 4 + 1) * HH + col], acc);
            acc = fmaf(xv.z, Wl[(k4 * 4 + 2) * HH + col], acc);
            acc = fmaf(xv.w, Wl[(k4 * 4 + 3) * HH + col], acc);
        }
        Y[(size_t)r * HH + col] = acc * dis[r];
    }
}

// ---------- gather conv: out[d] = relu(dd*(sum Hs[src] + Hs[d]) + b) ----------
// One wave per node, wave-uniform gather addresses (one 256B segment per load
// instruction). 4-deep unroll + pipelined index prefetch -> ~4 independent
// gathers in flight per wave.
template<bool POOL>
__global__ __launch_bounds__(256) void
k_gconv(const int* __restrict__ row_ptr, const int* __restrict__ srcs,
        const float* __restrict__ dis, const float* __restrict__ Hs,
        const float* __restrict__ b, float* __restrict__ Out,
        const int* __restrict__ batch, float* __restrict__ g) {
    const int node = blockIdx.x * 4 + (threadIdx.x >> 6);
    const int lane = threadIdx.x & 63;
    const int p1 = row_ptr[node + 1];
    int p = row_ptr[node];
    float a0 = 0.f, a1 = 0.f, a2 = 0.f, a3 = 0.f;
    int s0, s1, s2, s3;
    if (p + 4 <= p1) { s0 = srcs[p]; s1 = srcs[p+1]; s2 = srcs[p+2]; s3 = srcs[p+3]; }
    while (p + 4 <= p1) {
        const int q = p + 4;
        int t0, t1, t2, t3;
        if (q + 4 <= p1) { t0 = srcs[q]; t1 = srcs[q+1]; t2 = srcs[q+2]; t3 = srcs[q+3]; }
        a0 += Hs[(size_t)s0 * HH + lane];
        a1 += Hs[(size_t)s1 * HH + lane];
        a2 += Hs[(size_t)s2 * HH + lane];
        a3 += Hs[(size_t)s3 * HH + lane];
        s0 = t0; s1 = t1; s2 = t2; s3 = t3;
        p = q;
    }
    for (; p < p1; ++p) a0 += Hs[(size_t)srcs[p] * HH + lane];
    float acc = (a0 + a1) + (a2 + a3);
    const float dd = dis[node];
    float v = (acc + Hs[(size_t)node * HH + lane]) * dd + b[lane];
    v = fmaxf(v, 0.0f);
    if (POOL) {
        unsafeAtomicAdd(&g[(size_t)batch[node] * HH + lane], v);
    } else {
        Out[(size_t)node * HH + lane] = v;
    }
}

// ---------- head ----------
__global__ void k_head1(const float* __restrict__ g, const float* __restrict__ W,
                        const float* __restrict__ b, float* __restrict__ g2) {
    const int idx = blockIdx.x * 256 + threadIdx.x;
    const int row = idx >> 6;
    const int col = idx & 63;
    const float* gr = g + (size_t)row * HH;
    float acc = b[col];
#pragma unroll
    for (int k = 0; k < HH; ++k) acc = fmaf(gr[k], W[k * HH + col], acc);
    g2[idx] = acc > 0.0f ? acc : 0.0f;
}

__global__ void k_head2(const float* __restrict__ g2, const float* __restrict__ W,
                        const float* __restrict__ b, float* __restrict__ out) {
    const int r = threadIdx.x;
    if (r >= GG) return;
    const float* gr = g2 + (size_t)r * HH;
    float acc = 0.0f;
#pragma unroll
    for (int k = 0; k < HH; ++k) acc = fmaf(gr[k], W[k], acc);
    out[r] = acc + b[0];
}

extern "C" void kernel_launch(void* const* d_in, const int* in_sizes, int n_in,
                              void* d_out, int out_size, void* d_ws, size_t ws_size,
                              hipStream_t stream) {
    const float* x   = (const float*)d_in[0];
    const int*   ei  = (const int*)d_in[1];
    const int*   bat = (const int*)d_in[2];
    const float* W1  = (const float*)d_in[3];
    const float* b1  = (const float*)d_in[4];
    const float* W2  = (const float*)d_in[5];
    const float* b2  = (const float*)d_in[6];
    const float* Wl1 = (const float*)d_in[7];
    const float* bl1 = (const float*)d_in[8];
    const float* Wl2 = (const float*)d_in[9];
    const float* bl2 = (const float*)d_in[10];
    float* out = (float*)d_out;

    char* w = (char*)d_ws;
    float* dis     = (float*)(w);                    // 400128 B
    int*   cnt     = (int*)  (w + 400128);           // 400128 B
    int*   row_ptr = (int*)  (w + 800256);           // 400384 B (N+1)
    int*   cursor  = (int*)  (w + 1200640);          // 400128 B
    int*   part    = (int*)  (w + 1600768);          // 2048 B
    int*   srcs    = (int*)  (w + 1602816);          // 4000000 B
    float* B       = (float*)(w + 5602816);          // 25.6 MB
    float* A       = (float*)(w + 31202816);         // 25.6 MB
    float* g       = (float*)(w + 56802816);         // 32 KB
    float* g2      = g + GG * HH;

    // ---- CSR build (once; reused by both convs) ----
    hipMemsetAsync(cnt, 0, (size_t)NN * sizeof(int), stream);
    k_hist <<<(EE + 255) / 256, 256, 0, stream>>>(ei, cnt);
    k_scan1<<<NB, 256, 0, stream>>>(cnt, part);
    k_scan2<<<1, 512, 0, stream>>>(part);
    k_scan3<<<NB, 256, 0, stream>>>(cnt, part, row_ptr, cursor, dis);
    k_place<<<(EE + 255) / 256, 256, 0, stream>>>(ei, cursor, srcs);

    // ---- conv1 ----
    k_matmul_s<FF><<<(NN + 31) / 32, 256, 0, stream>>>(x, W1, dis, B);
    k_gconv<false><<<NN / 4, 256, 0, stream>>>(row_ptr, srcs, dis, B, b1, A, nullptr, nullptr);

    // ---- conv2 (pool fused) ----
    k_matmul_s<HH><<<(NN + 31) / 32, 256, 0, stream>>>(A, W2, dis, B);
    hipMemsetAsync(g, 0, (size_t)GG * HH * sizeof(float), stream);
    k_gconv<true><<<NN / 4, 256, 0, stream>>>(row_ptr, srcs, dis, B, b2, nullptr, bat, g);

    // ---- head ----
    k_head1<<<(GG * HH) / 256, 256, 0, stream>>>(g, Wl1, bl1, g2);
    k_head2<<<1, 128, 0, stream>>>(g2, Wl2, bl2, out);
}

// Round 5
// 336.007 us; speedup vs baseline: 2.0469x; 1.3275x over previous
//
#include <hip/hip_runtime.h>

#define NN 100000
#define EE 1000000
#define FF 128
#define HH 64
#define GG 128
#define NB 391   // scan blocks: 391*256 = 100096 >= NN

__device__ inline unsigned short f2bf(float f) {
    unsigned u = __float_as_uint(f);
    u += 0x7fffu + ((u >> 16) & 1u);
    return (unsigned short)(u >> 16);
}
__device__ inline float bf2f(unsigned short h) {
    return __uint_as_float((unsigned)h << 16);
}

// ---------- CSR build ----------
__global__ void k_hist(const int* __restrict__ ei, int* __restrict__ cnt) {
    int e = blockIdx.x * 256 + threadIdx.x;
    if (e < EE) atomicAdd(&cnt[ei[EE + e]], 1);
}

__global__ void k_scan1(const int* __restrict__ cnt, int* __restrict__ part) {
    int i = blockIdx.x * 256 + threadIdx.x;
    int v = (i < NN) ? cnt[i] : 0;
    for (int o = 1; o < 64; o <<= 1) v += __shfl_xor(v, o);
    __shared__ int ws[4];
    if ((threadIdx.x & 63) == 0) ws[threadIdx.x >> 6] = v;
    __syncthreads();
    if (threadIdx.x == 0) part[blockIdx.x] = ws[0] + ws[1] + ws[2] + ws[3];
}

__global__ void k_scan2(int* __restrict__ part) {   // exclusive scan, 1 block
    __shared__ int buf[512];
    int t = threadIdx.x;
    int v = (t < NB) ? part[t] : 0;
    buf[t] = v; __syncthreads();
    for (int o = 1; o < 512; o <<= 1) {
        int u = (t >= o) ? buf[t - o] : 0;
        __syncthreads();
        buf[t] += u;
        __syncthreads();
    }
    if (t < NB) part[t] = buf[t] - v;
}

__global__ void k_scan3(const int* __restrict__ cnt, const int* __restrict__ part,
                        int* __restrict__ row_ptr, int* __restrict__ cursor,
                        float* __restrict__ dis) {
    int i = blockIdx.x * 256 + threadIdx.x;
    int v = (i < NN) ? cnt[i] : 0;
    int lane = threadIdx.x & 63, w = threadIdx.x >> 6;
    int incl = v;
    for (int o = 1; o < 64; o <<= 1) { int u = __shfl_up(incl, o); if (lane >= o) incl += u; }
    __shared__ int ws[4];
    if (lane == 63) ws[w] = incl;
    __syncthreads();
    int woff = 0;
    for (int k = 0; k < w; ++k) woff += ws[k];
    int excl = incl - v + woff + part[blockIdx.x];
    if (i < NN) {
        row_ptr[i] = excl;
        cursor[i]  = excl;
        dis[i] = rsqrtf((float)(v + 1));
    }
    if (i == 0) row_ptr[NN] = EE;
}

__global__ void k_place(const int* __restrict__ ei, int* __restrict__ cursor,
                        int* __restrict__ srcs) {
    int e = blockIdx.x * 256 + threadIdx.x;
    if (e < EE) {
        int d = ei[EE + e];
        int p = atomicAdd(&cursor[d], 1);
        srcs[p] = ei[e];
    }
}

// ---------- dense: Y[N,64] = bf16( (X[N,K] @ W[K,64]) * dis[row] ) ----------
// Register-tiled: each thread does 4 rows x 4 cols; W via ds_read_b128
// reused across 4 rows -> 1 LDS instr per 16 FMA (was 1 per 1).
template<int K>
__global__ __launch_bounds__(256) void
k_matmul_b(const float* __restrict__ X, const float* __restrict__ W,
           const float* __restrict__ dis, unsigned short* __restrict__ Y) {
    __shared__ float Wl[K * HH];
    for (int i = threadIdx.x; i < K * HH; i += 256) Wl[i] = W[i];
    __syncthreads();
    const int lane = threadIdx.x & 63;
    const int wv   = threadIdx.x >> 6;       // 0..3
    const int c4   = (lane & 15) * 4;        // col group
    const int rsg  = lane >> 4;              // 0..3 row subgroup
    const int r0   = blockIdx.x * 64 + wv * 16 + rsg * 4;

    const float* xr0; const float* xr1; const float* xr2; const float* xr3;
    {
        int a = r0,     b_ = r0 + 1, c = r0 + 2, d = r0 + 3;
        if (a > NN - 1) a = NN - 1;
        if (b_ > NN - 1) b_ = NN - 1;
        if (c > NN - 1) c = NN - 1;
        if (d > NN - 1) d = NN - 1;
        xr0 = X + (size_t)a * K; xr1 = X + (size_t)b_ * K;
        xr2 = X + (size_t)c * K; xr3 = X + (size_t)d * K;
    }
    float4 acc0 = {0,0,0,0}, acc1 = {0,0,0,0}, acc2 = {0,0,0,0}, acc3 = {0,0,0,0};

#pragma unroll 8
    for (int k4 = 0; k4 < K / 4; ++k4) {
        const float4 x0 = *(const float4*)(xr0 + k4 * 4);
        const float4 x1 = *(const float4*)(xr1 + k4 * 4);
        const float4 x2 = *(const float4*)(xr2 + k4 * 4);
        const float4 x3 = *(const float4*)(xr3 + k4 * 4);
        const float4 w0 = *(const float4*)&Wl[(k4 * 4 + 0) * HH + c4];
        const float4 w1 = *(const float4*)&Wl[(k4 * 4 + 1) * HH + c4];
        const float4 w2 = *(const float4*)&Wl[(k4 * 4 + 2) * HH + c4];
        const float4 w3 = *(const float4*)&Wl[(k4 * 4 + 3) * HH + c4];
#define FMA4(A, XS) \
        A.x = fmaf(XS.x, w0.x, A.x); A.y = fmaf(XS.x, w0.y, A.y); \
        A.z = fmaf(XS.x, w0.z, A.z); A.w = fmaf(XS.x, w0.w, A.w); \
        A.x = fmaf(XS.y, w1.x, A.x); A.y = fmaf(XS.y, w1.y, A.y); \
        A.z = fmaf(XS.y, w1.z, A.z); A.w = fmaf(XS.y, w1.w, A.w); \
        A.x = fmaf(XS.z, w2.x, A.x); A.y = fmaf(XS.z, w2.y, A.y); \
        A.z = fmaf(XS.z, w2.z, A.z); A.w = fmaf(XS.z, w2.w, A.w); \
        A.x = fmaf(XS.w, w3.x, A.x); A.y = fmaf(XS.w, w3.y, A.y); \
        A.z = fmaf(XS.w, w3.z, A.z); A.w = fmaf(XS.w, w3.w, A.w);
        FMA4(acc0, x0) FMA4(acc1, x1) FMA4(acc2, x2) FMA4(acc3, x3)
#undef FMA4
    }
#define STORE(I, A) { \
        const int r = r0 + I; \
        if (r < NN) { \
            const float d = dis[r]; \
            ushort4 o; \
            o.x = f2bf(A.x * d); o.y = f2bf(A.y * d); \
            o.z = f2bf(A.z * d); o.w = f2bf(A.w * d); \
            *(ushort4*)(Y + (size_t)r * HH + c4) = o; \
        } }
    STORE(0, acc0) STORE(1, acc1) STORE(2, acc2) STORE(3, acc3)
#undef STORE
}

// ---------- gather conv: out[d] = relu(dd*(sum Hs[src] + Hs[d]) + b) ----------
// Hs rows are bf16 (128B). Wave-uniform addresses, 4-deep unroll + index
// prefetch. Accumulate fp32.
template<bool POOL>
__global__ __launch_bounds__(256) void
k_gconv(const int* __restrict__ row_ptr, const int* __restrict__ srcs,
        const float* __restrict__ dis, const unsigned short* __restrict__ Hs,
        const float* __restrict__ b, float* __restrict__ Out,
        const int* __restrict__ batch, float* __restrict__ g) {
    const int node = blockIdx.x * 4 + (threadIdx.x >> 6);
    const int lane = threadIdx.x & 63;
    const int p1 = row_ptr[node + 1];
    int p = row_ptr[node];
    float a0 = 0.f, a1 = 0.f, a2 = 0.f, a3 = 0.f;
    int s0, s1, s2, s3;
    if (p + 4 <= p1) { s0 = srcs[p]; s1 = srcs[p+1]; s2 = srcs[p+2]; s3 = srcs[p+3]; }
    while (p + 4 <= p1) {
        const int q = p + 4;
        int t0, t1, t2, t3;
        if (q + 4 <= p1) { t0 = srcs[q]; t1 = srcs[q+1]; t2 = srcs[q+2]; t3 = srcs[q+3]; }
        a0 += bf2f(Hs[(size_t)s0 * HH + lane]);
        a1 += bf2f(Hs[(size_t)s1 * HH + lane]);
        a2 += bf2f(Hs[(size_t)s2 * HH + lane]);
        a3 += bf2f(Hs[(size_t)s3 * HH + lane]);
        s0 = t0; s1 = t1; s2 = t2; s3 = t3;
        p = q;
    }
    for (; p < p1; ++p) a0 += bf2f(Hs[(size_t)srcs[p] * HH + lane]);
    float acc = (a0 + a1) + (a2 + a3);
    const float dd = dis[node];
    float v = (acc + bf2f(Hs[(size_t)node * HH + lane])) * dd + b[lane];
    v = fmaxf(v, 0.0f);
    if (POOL) {
        unsafeAtomicAdd(&g[(size_t)batch[node] * HH + lane], v);
    } else {
        Out[(size_t)node * HH + lane] = v;
    }
}

// ---------- head ----------
__global__ void k_head1(const float* __restrict__ g, const float* __restrict__ W,
                        const float* __restrict__ b, float* __restrict__ g2) {
    const int idx = blockIdx.x * 256 + threadIdx.x;
    const int row = idx >> 6;
    const int col = idx & 63;
    const float* gr = g + (size_t)row * HH;
    float acc = b[col];
#pragma unroll
    for (int k = 0; k < HH; ++k) acc = fmaf(gr[k], W[k * HH + col], acc);
    g2[idx] = acc > 0.0f ? acc : 0.0f;
}

__global__ void k_head2(const float* __restrict__ g2, const float* __restrict__ W,
                        const float* __restrict__ b, float* __restrict__ out) {
    const int r = threadIdx.x;
    if (r >= GG) return;
    const float* gr = g2 + (size_t)r * HH;
    float acc = 0.0f;
#pragma unroll
    for (int k = 0; k < HH; ++k) acc = fmaf(gr[k], W[k], acc);
    out[r] = acc + b[0];
}

extern "C" void kernel_launch(void* const* d_in, const int* in_sizes, int n_in,
                              void* d_out, int out_size, void* d_ws, size_t ws_size,
                              hipStream_t stream) {
    const float* x   = (const float*)d_in[0];
    const int*   ei  = (const int*)d_in[1];
    const int*   bat = (const int*)d_in[2];
    const float* W1  = (const float*)d_in[3];
    const float* b1  = (const float*)d_in[4];
    const float* W2  = (const float*)d_in[5];
    const float* b2  = (const float*)d_in[6];
    const float* Wl1 = (const float*)d_in[7];
    const float* bl1 = (const float*)d_in[8];
    const float* Wl2 = (const float*)d_in[9];
    const float* bl2 = (const float*)d_in[10];
    float* out = (float*)d_out;

    char* w = (char*)d_ws;
    float* dis     = (float*)(w);                    // 400128 B
    int*   cnt     = (int*)  (w + 400128);           // 400128 B
    int*   row_ptr = (int*)  (w + 800256);           // 400384 B (N+1)
    int*   cursor  = (int*)  (w + 1200640);          // 400128 B
    int*   part    = (int*)  (w + 1600768);          // 2048 B
    int*   srcs    = (int*)  (w + 1602816);          // 4000000 B
    unsigned short* B = (unsigned short*)(w + 5602816); // 12.8 MB (bf16)
    float* A       = (float*)(w + 31202816);         // 25.6 MB
    float* g       = (float*)(w + 56802816);         // 32 KB
    float* g2      = g + GG * HH;

    // ---- CSR build (once; reused by both convs) ----
    hipMemsetAsync(cnt, 0, (size_t)NN * sizeof(int), stream);
    k_hist <<<(EE + 255) / 256, 256, 0, stream>>>(ei, cnt);
    k_scan1<<<NB, 256, 0, stream>>>(cnt, part);
    k_scan2<<<1, 512, 0, stream>>>(part);
    k_scan3<<<NB, 256, 0, stream>>>(cnt, part, row_ptr, cursor, dis);
    k_place<<<(EE + 255) / 256, 256, 0, stream>>>(ei, cursor, srcs);

    // ---- conv1 ----
    k_matmul_b<FF><<<(NN + 63) / 64, 256, 0, stream>>>(x, W1, dis, B);
    k_gconv<false><<<NN / 4, 256, 0, stream>>>(row_ptr, srcs, dis, B, b1, A, nullptr, nullptr);

    // ---- conv2 (pool fused) ----
    k_matmul_b<HH><<<(NN + 63) / 64, 256, 0, stream>>>(A, W2, dis, B);
    hipMemsetAsync(g, 0, (size_t)GG * HH * sizeof(float), stream);
    k_gconv<true><<<NN / 4, 256, 0, stream>>>(row_ptr, srcs, dis, B, b2, nullptr, bat, g);

    // ---- head ----
    k_head1<<<(GG * HH) / 256, 256, 0, stream>>>(g, Wl1, bl1, g2);
    k_head2<<<1, 128, 0, stream>>>(g2, Wl2, bl2, out);
}

// Round 6
// 319.645 us; speedup vs baseline: 2.1517x; 1.0512x over previous
//
#include <hip/hip_runtime.h>

#define NN 100000
#define EE 1000000
#define FF 128
#define HH 64
#define GG 128
#define NB 391   // scan blocks: 391*256 = 100096 >= NN

__device__ inline unsigned short f2bf(float f) {
    unsigned u = __float_as_uint(f);
    u += 0x7fffu + ((u >> 16) & 1u);
    return (unsigned short)(u >> 16);
}
__device__ inline float bf2f(unsigned short h) {
    return __uint_as_float((unsigned)h << 16);
}

// ---------- CSR build ----------
__global__ void k_hist(const int* __restrict__ ei, int* __restrict__ cnt) {
    int e = blockIdx.x * 256 + threadIdx.x;
    if (e < EE) atomicAdd(&cnt[ei[EE + e]], 1);
}

__global__ void k_scan1(const int* __restrict__ cnt, int* __restrict__ part) {
    int i = blockIdx.x * 256 + threadIdx.x;
    int v = (i < NN) ? cnt[i] : 0;
    for (int o = 1; o < 64; o <<= 1) v += __shfl_xor(v, o);
    __shared__ int ws[4];
    if ((threadIdx.x & 63) == 0) ws[threadIdx.x >> 6] = v;
    __syncthreads();
    if (threadIdx.x == 0) part[blockIdx.x] = ws[0] + ws[1] + ws[2] + ws[3];
}

__global__ void k_scan2(int* __restrict__ part) {   // exclusive scan, 1 block
    __shared__ int buf[512];
    int t = threadIdx.x;
    int v = (t < NB) ? part[t] : 0;
    buf[t] = v; __syncthreads();
    for (int o = 1; o < 512; o <<= 1) {
        int u = (t >= o) ? buf[t - o] : 0;
        __syncthreads();
        buf[t] += u;
        __syncthreads();
    }
    if (t < NB) part[t] = buf[t] - v;
}

__global__ void k_scan3(const int* __restrict__ cnt, const int* __restrict__ part,
                        int* __restrict__ row_ptr, int* __restrict__ cursor,
                        float* __restrict__ dis) {
    int i = blockIdx.x * 256 + threadIdx.x;
    int v = (i < NN) ? cnt[i] : 0;
    int lane = threadIdx.x & 63, w = threadIdx.x >> 6;
    int incl = v;
    for (int o = 1; o < 64; o <<= 1) { int u = __shfl_up(incl, o); if (lane >= o) incl += u; }
    __shared__ int ws[4];
    if (lane == 63) ws[w] = incl;
    __syncthreads();
    int woff = 0;
    for (int k = 0; k < w; ++k) woff += ws[k];
    int excl = incl - v + woff + part[blockIdx.x];
    if (i < NN) {
        row_ptr[i] = excl;
        cursor[i]  = excl;
        dis[i] = rsqrtf((float)(v + 1));
    }
    if (i == 0) row_ptr[NN] = EE;
}

__global__ void k_place(const int* __restrict__ ei, int* __restrict__ cursor,
                        int* __restrict__ srcs) {
    int e = blockIdx.x * 256 + threadIdx.x;
    if (e < EE) {
        int d = ei[EE + e];
        int p = atomicAdd(&cursor[d], 1);
        srcs[p] = ei[e];
    }
}

// ---------- dense: Y[N,64] = bf16( (X[N,K] @ W[K,64]) * dis[row] ) ----------
template<int K>
__global__ __launch_bounds__(256) void
k_matmul_b(const float* __restrict__ X, const float* __restrict__ W,
           const float* __restrict__ dis, unsigned short* __restrict__ Y) {
    __shared__ float Wl[K * HH];
    for (int i = threadIdx.x; i < K * HH; i += 256) Wl[i] = W[i];
    __syncthreads();
    const int lane = threadIdx.x & 63;
    const int wv   = threadIdx.x >> 6;       // 0..3
    const int c4   = (lane & 15) * 4;        // col group
    const int rsg  = lane >> 4;              // 0..3 row subgroup
    const int r0   = blockIdx.x * 64 + wv * 16 + rsg * 4;

    const float* xr0; const float* xr1; const float* xr2; const float* xr3;
    {
        int a = r0,     b_ = r0 + 1, c = r0 + 2, d = r0 + 3;
        if (a > NN - 1) a = NN - 1;
        if (b_ > NN - 1) b_ = NN - 1;
        if (c > NN - 1) c = NN - 1;
        if (d > NN - 1) d = NN - 1;
        xr0 = X + (size_t)a * K; xr1 = X + (size_t)b_ * K;
        xr2 = X + (size_t)c * K; xr3 = X + (size_t)d * K;
    }
    float4 acc0 = {0,0,0,0}, acc1 = {0,0,0,0}, acc2 = {0,0,0,0}, acc3 = {0,0,0,0};

#pragma unroll 8
    for (int k4 = 0; k4 < K / 4; ++k4) {
        const float4 x0 = *(const float4*)(xr0 + k4 * 4);
        const float4 x1 = *(const float4*)(xr1 + k4 * 4);
        const float4 x2 = *(const float4*)(xr2 + k4 * 4);
        const float4 x3 = *(const float4*)(xr3 + k4 * 4);
        const float4 w0 = *(const float4*)&Wl[(k4 * 4 + 0) * HH + c4];
        const float4 w1 = *(const float4*)&Wl[(k4 * 4 + 1) * HH + c4];
        const float4 w2 = *(const float4*)&Wl[(k4 * 4 + 2) * HH + c4];
        const float4 w3 = *(const float4*)&Wl[(k4 * 4 + 3) * HH + c4];
#define FMA4(A, XS) \
        A.x = fmaf(XS.x, w0.x, A.x); A.y = fmaf(XS.x, w0.y, A.y); \
        A.z = fmaf(XS.x, w0.z, A.z); A.w = fmaf(XS.x, w0.w, A.w); \
        A.x = fmaf(XS.y, w1.x, A.x); A.y = fmaf(XS.y, w1.y, A.y); \
        A.z = fmaf(XS.y, w1.z, A.z); A.w = fmaf(XS.y, w1.w, A.w); \
        A.x = fmaf(XS.z, w2.x, A.x); A.y = fmaf(XS.z, w2.y, A.y); \
        A.z = fmaf(XS.z, w2.z, A.z); A.w = fmaf(XS.z, w2.w, A.w); \
        A.x = fmaf(XS.w, w3.x, A.x); A.y = fmaf(XS.w, w3.y, A.y); \
        A.z = fmaf(XS.w, w3.z, A.z); A.w = fmaf(XS.w, w3.w, A.w);
        FMA4(acc0, x0) FMA4(acc1, x1) FMA4(acc2, x2) FMA4(acc3, x3)
#undef FMA4
    }
#define STORE(I, A) { \
        const int r = r0 + I; \
        if (r < NN) { \
            const float d = dis[r]; \
            ushort4 o; \
            o.x = f2bf(A.x * d); o.y = f2bf(A.y * d); \
            o.z = f2bf(A.z * d); o.w = f2bf(A.w * d); \
            *(ushort4*)(Y + (size_t)r * HH + c4) = o; \
        } }
    STORE(0, acc0) STORE(1, acc1) STORE(2, acc2) STORE(3, acc3)
#undef STORE
}

// ---------- gather conv ----------
// Items = deg edges + 1 self row. uint2/lane, 16 lanes per 128B bf16 row ->
// one load gathers 4 rows. Batch = 2 loads (8 items); software pipeline keeps
// next batch's gathers in flight while consuming current (issue order:
// idx[b+1] before val[b], so val waits never drain the pipe).
template<bool POOL>
__global__ __launch_bounds__(256) void
k_gconv(const int* __restrict__ row_ptr, const int* __restrict__ srcs,
        const float* __restrict__ dis, const unsigned short* __restrict__ Hs,
        const float* __restrict__ b, float* __restrict__ Out,
        const int* __restrict__ batch, float* __restrict__ g) {
    const int node = blockIdx.x * 4 + (threadIdx.x >> 6);
    const int lane = threadIdx.x & 63;
    const int li   = lane & 15;       // col-quad within row
    const int qr   = lane >> 4;       // row slot 0..3 within a load
    const int p0   = row_ptr[node];
    const int deg  = row_ptr[node + 1] - p0;
    const int items  = deg + 1;              // + self
    const int nbatch = (items + 7) >> 3;     // 8 items / batch

    float ac0 = 0.f, ac1 = 0.f, ac2 = 0.f, ac3 = 0.f;

#define IDX(bi, dA, dB) { \
        const int iA = 8 * (bi) + qr, iB = iA + 4; \
        dA = srcs[p0 + (iA < deg ? iA : 0)]; \
        dB = srcs[p0 + (iB < deg ? iB : 0)]; }
#define VAL(bi, sA, sB, vA, vB) { \
        const int iA = 8 * (bi) + qr, iB = iA + 4; \
        const int rA = (iA < deg) ? sA : node; \
        const int rB = (iB < deg) ? sB : node; \
        vA = *(const uint2*)(Hs + (size_t)rA * HH + li * 4); \
        vB = *(const uint2*)(Hs + (size_t)rB * HH + li * 4); }
#define CONSUME(bi, vA, vB) { \
        const int iA = 8 * (bi) + qr, iB = iA + 4; \
        const unsigned m0 = (iA <= deg) ? vA.x : 0u; \
        const unsigned m1 = (iA <= deg) ? vA.y : 0u; \
        const unsigned m2 = (iB <= deg) ? vB.x : 0u; \
        const unsigned m3 = (iB <= deg) ? vB.y : 0u; \
        ac0 += bf2f((unsigned short)m0);  ac1 += bf2f((unsigned short)(m0 >> 16)); \
        ac2 += bf2f((unsigned short)m1);  ac3 += bf2f((unsigned short)(m1 >> 16)); \
        ac0 += bf2f((unsigned short)m2);  ac1 += bf2f((unsigned short)(m2 >> 16)); \
        ac2 += bf2f((unsigned short)m3);  ac3 += bf2f((unsigned short)(m3 >> 16)); }

    int sA0, sA1, sB0, sB1;
    uint2 vA0, vA1;
    IDX(0, sA0, sA1);
    VAL(0, sA0, sA1, vA0, vA1);   // waits idx0, issues val0
    IDX(1, sB0, sB1);             // idx1 in flight behind val0
    for (int bi = 1; bi < nbatch; ++bi) {
        uint2 vB0, vB1;
        VAL(bi, sB0, sB1, vB0, vB1);   // waits idx[bi] only; val[bi-1] stays in flight
        IDX(bi + 1, sB0, sB1);         // clamped beyond nbatch; cheap L2 hits
        CONSUME(bi - 1, vA0, vA1);     // waits val[bi-1]; val[bi] stays in flight
        vA0 = vB0; vA1 = vB1;
    }
    CONSUME(nbatch - 1, vA0, vA1);
#undef IDX
#undef VAL
#undef CONSUME

    // reduce across the 4 row slots
    ac0 += __shfl_xor(ac0, 16); ac0 += __shfl_xor(ac0, 32);
    ac1 += __shfl_xor(ac1, 16); ac1 += __shfl_xor(ac1, 32);
    ac2 += __shfl_xor(ac2, 16); ac2 += __shfl_xor(ac2, 32);
    ac3 += __shfl_xor(ac3, 16); ac3 += __shfl_xor(ac3, 32);
    // redistribute so lane holds col = lane
    const float c0 = __shfl(ac0, lane >> 2);
    const float c1 = __shfl(ac1, lane >> 2);
    const float c2 = __shfl(ac2, lane >> 2);
    const float c3 = __shfl(ac3, lane >> 2);
    const int m = lane & 3;
    float acc = (m == 0) ? c0 : (m == 1) ? c1 : (m == 2) ? c2 : c3;

    const float dd = dis[node];
    float v = acc * dd + b[lane];
    v = fmaxf(v, 0.0f);
    if (POOL) {
        unsafeAtomicAdd(&g[(size_t)batch[node] * HH + lane], v);
    } else {
        Out[(size_t)node * HH + lane] = v;
    }
}

// ---------- head ----------
__global__ void k_head1(const float* __restrict__ g, const float* __restrict__ W,
                        const float* __restrict__ b, float* __restrict__ g2) {
    const int idx = blockIdx.x * 256 + threadIdx.x;
    const int row = idx >> 6;
    const int col = idx & 63;
    const float* gr = g + (size_t)row * HH;
    float acc = b[col];
#pragma unroll
    for (int k = 0; k < HH; ++k) acc = fmaf(gr[k], W[k * HH + col], acc);
    g2[idx] = acc > 0.0f ? acc : 0.0f;
}

__global__ void k_head2(const float* __restrict__ g2, const float* __restrict__ W,
                        const float* __restrict__ b, float* __restrict__ out) {
    const int r = threadIdx.x;
    if (r >= GG) return;
    const float* gr = g2 + (size_t)r * HH;
    float acc = 0.0f;
#pragma unroll
    for (int k = 0; k < HH; ++k) acc = fmaf(gr[k], W[k], acc);
    out[r] = acc + b[0];
}

extern "C" void kernel_launch(void* const* d_in, const int* in_sizes, int n_in,
                              void* d_out, int out_size, void* d_ws, size_t ws_size,
                              hipStream_t stream) {
    const float* x   = (const float*)d_in[0];
    const int*   ei  = (const int*)d_in[1];
    const int*   bat = (const int*)d_in[2];
    const float* W1  = (const float*)d_in[3];
    const float* b1  = (const float*)d_in[4];
    const float* W2  = (const float*)d_in[5];
    const float* b2  = (const float*)d_in[6];
    const float* Wl1 = (const float*)d_in[7];
    const float* bl1 = (const float*)d_in[8];
    const float* Wl2 = (const float*)d_in[9];
    const float* bl2 = (const float*)d_in[10];
    float* out = (float*)d_out;

    char* w = (char*)d_ws;
    float* dis     = (float*)(w);                    // 400128 B
    int*   cnt     = (int*)  (w + 400128);           // 400128 B
    int*   row_ptr = (int*)  (w + 800256);           // 400384 B (N+1)
    int*   cursor  = (int*)  (w + 1200640);          // 400128 B
    int*   part    = (int*)  (w + 1600768);          // 2048 B
    int*   srcs    = (int*)  (w + 1602816);          // 4000000 B
    unsigned short* B = (unsigned short*)(w + 5602816); // 12.8 MB (bf16)
    float* A       = (float*)(w + 31202816);         // 25.6 MB
    float* g       = (float*)(w + 56802816);         // 32 KB
    float* g2      = g + GG * HH;

    // ---- CSR build (once; reused by both convs) ----
    hipMemsetAsync(cnt, 0, (size_t)NN * sizeof(int), stream);
    k_hist <<<(EE + 255) / 256, 256, 0, stream>>>(ei, cnt);
    k_scan1<<<NB, 256, 0, stream>>>(cnt, part);
    k_scan2<<<1, 512, 0, stream>>>(part);
    k_scan3<<<NB, 256, 0, stream>>>(cnt, part, row_ptr, cursor, dis);
    k_place<<<(EE + 255) / 256, 256, 0, stream>>>(ei, cursor, srcs);

    // ---- conv1 ----
    k_matmul_b<FF><<<(NN + 63) / 64, 256, 0, stream>>>(x, W1, dis, B);
    k_gconv<false><<<NN / 4, 256, 0, stream>>>(row_ptr, srcs, dis, B, b1, A, nullptr, nullptr);

    // ---- conv2 (pool fused) ----
    k_matmul_b<HH><<<(NN + 63) / 64, 256, 0, stream>>>(A, W2, dis, B);
    hipMemsetAsync(g, 0, (size_t)GG * HH * sizeof(float), stream);
    k_gconv<true><<<NN / 4, 256, 0, stream>>>(row_ptr, srcs, dis, B, b2, nullptr, bat, g);

    // ---- head ----
    k_head1<<<(GG * HH) / 256, 256, 0, stream>>>(g, Wl1, bl1, g2);
    k_head2<<<1, 128, 0, stream>>>(g2, Wl2, bl2, out);
}